// Round 18
// baseline (196.324 us; speedup 1.0000x reference)
//
#include <hip/hip_runtime.h>
#include <math.h>

typedef unsigned short u16;
typedef unsigned int u32;
typedef unsigned long long u64;
typedef __attribute__((ext_vector_type(8))) short short8;
typedef __attribute__((ext_vector_type(4))) float f32x4;
typedef __attribute__((ext_vector_type(16))) float f32x16;

// B=8, C=256, H=W=64, L=4096, NH=8, HD=32. Inputs/outputs fp32.
static constexpr float SCALE = 0.17677669529663687f;          // 1/sqrt(32)
static constexpr float C2    = 0.17677669529663687f / 4096.f; // (scale/L) = c^2

__device__ __forceinline__ float bf2f(u16 u){
  union { u32 i; float f; } v; v.i = ((u32)u) << 16; return v.f;
}
__device__ __forceinline__ u16 f2bf(float f){
  union { float fl; u32 i; } v; v.fl = f;
  u32 r = v.i + 0x7fffu + ((v.i >> 16) & 1u);   // RNE
  return (u16)(r >> 16);
}
__device__ __forceinline__ float eluP(float x){ return x > 0.f ? x + 1.f : __expf(x); }
__device__ __forceinline__ float rfreq(int j){
  const float t[8] = {1.f, 0.2682695795f, 0.0719685673f, 0.0193069773f,
                      0.0051794747f, 0.0013894955f, 0.0003727594f, 1e-4f};
  return t[j];
}
// async global->LDS, 16B per lane; lds base must be wave-uniform
__device__ __forceinline__ void gload16(const u16* g, u16* l){
  __builtin_amdgcn_global_load_lds(
      (const __attribute__((address_space(1))) u32*)g,
      (__attribute__((address_space(3))) u32*)l, 16, 0, 0);
}

// ---------------- pre: x transpose + weight split + sincos table + zero buffers ----------------
// grid (64, 4, 12): z<8 -> xt for batch z; z>=8 -> weight prep (1024 virtual blocks)
__global__ __launch_bounds__(256) void k_pre(
    const float* __restrict__ x, const float* __restrict__ qw, const float* __restrict__ pw,
    u16* __restrict__ XT, u16* __restrict__ Whi, u16* __restrict__ Wlo,
    u16* __restrict__ Phi, u16* __restrict__ Plo, float* __restrict__ KM0,
    float* __restrict__ SCS, float* __restrict__ KVb)
{
  if (blockIdx.z < 8){
    __shared__ float t[64][65];
    int l0 = blockIdx.x * 64, c0 = blockIdx.y * 64, b = blockIdx.z;
    const float* xp = x + (((long)b * 256 + c0) << 12) + l0;
    #pragma unroll
    for (int rep = 0; rep < 4; rep++){
      int idx = threadIdx.x + rep * 256;
      int r = idx >> 4, ch = (idx & 15) * 4;
      float4 f = *(const float4*)&xp[((long)r << 12) + ch];
      t[r][ch] = f.x; t[r][ch+1] = f.y; t[r][ch+2] = f.z; t[r][ch+3] = f.w;
    }
    __syncthreads();
    int r2 = threadIdx.x >> 2, c8 = (threadIdx.x & 3) * 16;
    u32 w[8];
    #pragma unroll
    for (int j = 0; j < 8; j++){
      float v0 = t[c8 + 2*j][r2], v1 = t[c8 + 2*j + 1][r2];
      w[j] = (u32)f2bf(v0) | ((u32)f2bf(v1) << 16);
    }
    long ob = (((long)b << 12) << 8) + ((long)(l0 + r2) << 8) + c0 + c8;
    *(uint4*)&XT[ob]     = make_uint4(w[0], w[1], w[2], w[3]);
    *(uint4*)&XT[ob + 8] = make_uint4(w[4], w[5], w[6], w[7]);
  } else {
    int bid = (blockIdx.z - 8) * 256 + blockIdx.y * 64 + blockIdx.x;   // 0..1023
    int idx = bid * 256 + threadIdx.x;
    if (idx < 262144){
      // single-bf16 qkvo weights (lo-residual dropped: absmax unchanged at 1.22e-4,
      // error budget dominated by bf16 storage of intermediates — measured r14)
      Whi[idx] = f2bf(qw[idx]);
    }
    if (idx < 65536){
      float v = pw[idx]; u16 h = f2bf(v);
      Phi[idx] = h; Plo[idx] = f2bf(v - bf2f(h));
    }
    if (bid == 0){
      #pragma unroll
      for (int i = 0; i < 16; i++) KM0[threadIdx.x + i * 256] = 0.f;
    }
    if (bid == 1){
      // rope sincos table, computed ONCE: SCS[0..511]=sin, SCS[512..1023]=cos
      #pragma unroll
      for (int r = 0; r < 2; r++){
        int t2 = threadIdx.x + r * 256;          // 0..511
        int jj = t2 >> 6, pp = t2 & 63;
        float sn, cs; sincosf(rfreq(jj) * (float)pp, &sn, &cs);
        SCS[t2] = sn; SCS[512 + t2] = cs;
      }
    }
    if (bid >= 2 && bid < 10){
      // zero KVb (65536 floats) for k_mid's atomic accumulation
      int base = (bid - 2) * 8192 + threadIdx.x;
      #pragma unroll
      for (int i = 0; i < 32; i++) KVb[base + i * 256] = 0.f;
    }
  }
}

// ---------------- qkvo GEMM: BM=128 x BN=256, single-bf16 A, 3-buf counted-vmcnt ----------------
// r17 dbuf waited vmcnt(0) on loads issued one compute-phase (~300cy) earlier vs
// 400-900cy L2/HBM latency. 3 buffers (76KB LDS, STILL 2 blocks/CU) + vmcnt(6)
// give each stage two compute phases to land (T4; r5 gemmP precedent: helps when
// occupancy unchanged). waves_per_eu(2,2) prevents spill (r14/r15 lesson).
// Chunk swizzle: LDS chunk c of row r = global chunk c^((r>>1)&3).
__global__ __launch_bounds__(256)
__attribute__((amdgpu_waves_per_eu(2, 2)))
void k_gemmA(
    const u16* __restrict__ Whi_, const u16* __restrict__ Wlo_,
    const u16* __restrict__ Bh_,
    const float* __restrict__ bias, const float* __restrict__ SCS_,
    u16* __restrict__ Q16, u16* __restrict__ K16,
    u16* __restrict__ V16, u16* __restrict__ O16,
    float* __restrict__ KMb, float* __restrict__ VMb)
{
  __shared__ __align__(16) u16 AhS[3][4096];
  __shared__ __align__(16) u16 BhS[3][8192];
  __shared__ float scs[2][8][64];
  const int tid = threadIdx.x;
  const int nt = blockIdx.x, mt = blockIdx.y, b = blockIdx.z;   // nt fastest
  const int m0 = mt * 128, n0 = nt * 256;
  const int wave = tid >> 6, lane = tid & 63;
  const int wm = wave & 1, wn = wave >> 1, qu = lane >> 4, ln = lane & 15;
  const int range = m0 >> 8;                 // 0:q 1:k 2:v 3:o (block-uniform)

  const u16* bhp = Bh_ + (((long)b << 12) << 8);

  const int l4 = lane >> 2, c4 = lane & 3;
  const int gch = (c4 ^ ((l4 >> 1) & 3)) * 8;     // swizzled global col chunk (store side)
  const int fch = (qu ^ ((ln >> 1) & 3)) * 8;     // fragment read swizzle (read side)

  auto stage = [&](int buf, int kk){              // 6 vmem ops/thread
    #pragma unroll
    for (int t = 0; t < 2; t++){                  // A: 128 rows
      int rw = wave * 32 + t * 16;
      int ga = (m0 + rw + l4) * 256 + kk + gch;
      gload16(&Whi_[ga], &AhS[buf][rw * 32]);
    }
    #pragma unroll
    for (int t = 0; t < 4; t++){                  // B: 256 rows
      int rwb = wave * 16 + t * 64;
      long gb = (long)(n0 + rwb + l4) * 256 + kk + gch;
      gload16(&bhp[gb], &BhS[buf][rwb * 32]);
    }
  };

  f32x4 acc[4][8];
  #pragma unroll
  for (int im = 0; im < 4; im++)
    #pragma unroll
    for (int in = 0; in < 8; in++)
      #pragma unroll
      for (int r = 0; r < 4; r++) acc[im][in][r] = 0.f;

  stage(0, 0);                               // prologue: 2 stages in flight
  stage(1, 32);
  if (range == 1){                           // rope table: flat copy from global (no sincosf)
    #pragma unroll
    for (int r = 0; r < 4; r++){
      int idx = tid + r * 256;               // 0..1023
      ((float*)scs)[idx] = SCS_[idx];
    }
  }
  // drain LDS writes (scs) before first raw barrier (raw s_barrier doesn't drain lgkm)
  asm volatile("s_waitcnt lgkmcnt(0)" ::: "memory");

  #pragma unroll
  for (int ks = 0; ks < 8; ks++){
    // wait for buf[ks%3]'s 6 loads; keep the newer stage's 6 in flight (never 0 mid-loop)
    if (ks < 7) asm volatile("s_waitcnt vmcnt(6)" ::: "memory");
    else        asm volatile("s_waitcnt vmcnt(0)" ::: "memory");
    __builtin_amdgcn_s_barrier();
    __builtin_amdgcn_sched_barrier(0);
    if (ks < 6) stage((ks + 2) % 3, (ks + 2) * 32);   // overwrites buf read at ks-1 (barrier-protected)
    const u16* Ah = AhS[ks % 3];
    const u16* Bc = BhS[ks % 3];
    short8 fbh[8];
    #pragma unroll
    for (int in = 0; in < 8; in++){
      int row = wn * 128 + in * 16 + ln;         // row < 256
      fbh[in] = *(const short8*)&Bc[row * 32 + fch];
    }
    #pragma unroll
    for (int im = 0; im < 4; im++){
      int row = wm * 64 + im * 16 + ln;          // row < 128
      short8 fah = *(const short8*)&Ah[row * 32 + fch];
      #pragma unroll
      for (int in = 0; in < 8; in++){
        acc[im][in] = __builtin_amdgcn_mfma_f32_16x16x32_bf16(fah, fbh[in], acc[im][in], 0, 0, 0);
      }
    }
  }

  // epilogue: C/D layout col = lane&15 (n), row = quad*4 + reg (m)
  u16* dst = (range == 0) ? Q16 : (range == 1) ? K16 : (range == 2) ? V16 : O16;
  #pragma unroll
  for (int im = 0; im < 4; im++){
    const int mb = m0 + wm * 64 + im * 16 + qu * 4;
    float v[4][8];
    #pragma unroll
    for (int r = 0; r < 4; r++){
      float bia = bias[mb + r];
      #pragma unroll
      for (int in = 0; in < 8; in++){
        float t = acc[im][in][r] + bia;
        v[r][in] = (range < 2) ? eluP(t) : t;
      }
    }
    if (range == 1 || range == 2){
      float* mbuf = (range == 1) ? KMb : VMb;
      #pragma unroll
      for (int r = 0; r < 4; r++){
        float s = 0.f;
        #pragma unroll
        for (int in = 0; in < 8; in++) s += v[r][in];
        s += __shfl_xor(s, 1); s += __shfl_xor(s, 2);
        s += __shfl_xor(s, 4); s += __shfl_xor(s, 8);
        if (ln == 0) atomicAdd(&mbuf[b * 256 + ((mb + r) & 255)], s);
      }
    }
    if (range == 1){
      const int p0 = (mb & 31) >> 1;
      #pragma unroll
      for (int half = 0; half < 2; half++){
        int p = p0 + half, j = p & 7;
        #pragma unroll
        for (int in = 0; in < 8; in++){
          int n = n0 + wn * 128 + in * 16 + ln;
          int pos = (p < 8) ? (n >> 6) : (n & 63);
          float sn = scs[0][j][pos], cs = scs[1][j][pos];
          float a = v[2*half][in], bb = v[2*half+1][in];
          v[2*half][in]   = a * cs - bb * sn;
          v[2*half+1][in] = bb * cs + a * sn;
        }
      }
    }
    #pragma unroll
    for (int r = 0; r < 4; r++){
      u16* rowp = dst + (((long)b * 256 + ((mb + r) & 255)) << 12);
      #pragma unroll
      for (int in = 0; in < 8; in++){
        int n = n0 + wn * 128 + in * 16 + ln;
        rowp[n] = f2bf(v[r][in]);
      }
    }
  }
}

// ---------------- mid: kv (4-way L-split, 256 blocks) + lepe (8-row window reuse) ----------------
// grid (4, 264, 8): y<8 -> kv partial block; y>=8 -> lepe(ht=x, ch=y-8, b=z)
__global__ __launch_bounds__(256) void k_mid(
    const u16* __restrict__ K16, const u16* __restrict__ V16,
    const float* __restrict__ lw, const float* __restrict__ lb,
    u16* __restrict__ Tb16, float* __restrict__ KVb)
{
  if (blockIdx.y >= 8){
    __shared__ float tile[20][68];
    int ht = blockIdx.x, ch = blockIdx.y - 8, b = blockIdx.z;
    int h0 = ht * 16;
    const u16* vp = V16 + (((long)b * 256 + ch) << 12);
    const float* __restrict__ wlp = lw + ch * 25;   // block-uniform -> scalar loads
    for (int idx = threadIdx.x; idx < 20 * 68; idx += 256){
      int r = idx / 68, c = idx % 68;
      int gh = h0 + r - 2, gw = c - 2;
      float v = 0.f;
      if (gh >= 0 && gh < 64 && gw >= 0 && gw < 64) v = bf2f(vp[(gh << 6) + gw]);
      tile[r][c] = v;
    }
    __syncthreads();
    const float bia = lb[ch];
    // thread -> 4 CONSECUTIVE rows: per col j, load the 8-row strip once (40 ds_reads vs 100)
    const int ow = threadIdx.x & 63, oh0 = (threadIdx.x >> 6) * 4;
    float s0 = bia, s1 = bia, s2 = bia, s3 = bia;
    #pragma unroll
    for (int j = 0; j < 5; j++){
      float c0 = tile[oh0+0][ow+j], c1 = tile[oh0+1][ow+j];
      float c2 = tile[oh0+2][ow+j], c3 = tile[oh0+3][ow+j];
      float c4 = tile[oh0+4][ow+j], c5 = tile[oh0+5][ow+j];
      float c6 = tile[oh0+6][ow+j], c7 = tile[oh0+7][ow+j];
      float w0 = wlp[j], w1 = wlp[5+j], w2 = wlp[10+j], w3 = wlp[15+j], w4 = wlp[20+j];
      s0 += c0*w0 + c1*w1 + c2*w2 + c3*w3 + c4*w4;
      s1 += c1*w0 + c2*w1 + c3*w2 + c4*w3 + c5*w4;
      s2 += c2*w0 + c3*w1 + c4*w2 + c5*w3 + c6*w4;
      s3 += c3*w0 + c4*w1 + c5*w2 + c6*w3 + c7*w4;
    }
    u16* tp = Tb16 + (((long)b * 256 + ch) << 12) + ((h0 + oh0) << 6) + ow;
    tp[0]   = f2bf(s0);
    tp[64]  = f2bf(s1);
    tp[128] = f2bf(s2);
    tp[192] = f2bf(s3);
  } else {
    __shared__ float red[4][1024];
    int kvIdx = blockIdx.y * 32 + blockIdx.z * 4 + blockIdx.x;   // 0..255
    int seg = kvIdx >> 6, rem = kvIdx & 63;
    int n = rem & 7, b = rem >> 3;
    const int tid = threadIdx.x, wave = tid >> 6, lane = tid & 63;
    const u16* kp = K16 + (((long)(b * 256 + n * 32)) << 12);
    const u16* vp = V16 + (((long)(b * 256 + n * 32)) << 12);
    const int m = lane & 31, kh = lane >> 5;
    const long row = ((long)m << 12);
    const int lbase = seg * 1024 + wave * 256;

    f32x16 acc;
    #pragma unroll
    for (int r = 0; r < 16; r++) acc[r] = 0.f;
    #pragma unroll 4
    for (int it = 0; it < 16; it++){
      int l = lbase + it * 16 + kh * 8;
      short8 a  = *(const short8*)&kp[row + l];
      short8 bf = *(const short8*)&vp[row + l];
      acc = __builtin_amdgcn_mfma_f32_32x32x16_bf16(a, bf, acc, 0, 0, 0);
    }
    #pragma unroll
    for (int reg = 0; reg < 16; reg++){
      int rr = (reg & 3) + 8 * (reg >> 2) + 4 * kh;
      red[wave][rr * 32 + m] = acc[reg];
    }
    __syncthreads();
    #pragma unroll
    for (int i = tid; i < 1024; i += 256){
      float s = red[0][i] + red[1][i] + red[2][i] + red[3][i];
      atomicAdd(&KVb[(((long)b * 8 + n) << 10) + i], s * C2);
    }
  }
}

// ---------------- res (+fused z): 256-thread blocks, uniform scalar kv/km/vm ----------------
__global__ __launch_bounds__(256) void k_res(
    const u16* __restrict__ Q16, const float* __restrict__ KMb,
    const float* __restrict__ KVb, const float* __restrict__ VMb,
    const u16* __restrict__ O16, const u16* __restrict__ Tb16,
    const float* __restrict__ SCS_, u16* __restrict__ TT16)
{
  __shared__ float scs[2][8][64];
  __shared__ __align__(16) u64 tts[256 * 9];   // [l][8 u64 + 1 pad]
  const int b = blockIdx.z, n = blockIdx.y, tid = threadIdx.x;
  #pragma unroll
  for (int r = 0; r < 4; r++){
    int idx = tid + r * 256;                 // 0..1023
    ((float*)scs)[idx] = SCS_[idx];
  }
  __syncthreads();

  const float* __restrict__ kv  = KVb + (((long)b * 8 + n) << 10);  // uniform
  const float* __restrict__ kmp = KMb + b * 256 + n * 32;           // uniform
  const float* __restrict__ vmp = VMb + b * 256 + n * 32;           // uniform

  const int l0 = blockIdx.x * 256;
  const int l = l0 + tid;
  const long cbase = ((long)(b * 256 + n * 32)) << 12;

  float q[32];
  #pragma unroll
  for (int d = 0; d < 32; d++) q[d] = bf2f(Q16[cbase + ((long)d << 12) + l]);
  float z = 0.f;
  #pragma unroll
  for (int d = 0; d < 32; d++) z += q[d] * kmp[d];
  z *= SCALE * (1.f / 4096.f);
  #pragma unroll
  for (int p = 0; p < 16; p++){
    int pos = (p < 8) ? (l >> 6) : (l & 63);
    float sn = scs[0][p & 7][pos], cs = scs[1][p & 7][pos];
    float q0 = q[2*p], q1 = q[2*p+1];
    q[2*p]   = q0 * cs - q1 * sn;
    q[2*p+1] = q1 * cs + q0 * sn;
  }

  float acc[32];
  #pragma unroll
  for (int e = 0; e < 32; e++) acc[e] = 0.f;
  #pragma unroll 8
  for (int d = 0; d < 32; d++){
    float qd = q[d];
    #pragma unroll
    for (int ec = 0; ec < 8; ec++){
      float4 kvv = *(const float4*)&kv[d * 32 + ec * 4];   // uniform -> scalar
      acc[ec*4+0] += qd * kvv.x;
      acc[ec*4+1] += qd * kvv.y;
      acc[ec*4+2] += qd * kvv.z;
      acc[ec*4+3] += qd * kvv.w;
    }
  }

  const float f = 1.f + 1.f / (z + 1e-6f);
  const float zv = z * (1.f / 4096.f);
  u32 w[16];
  #pragma unroll
  for (int e = 0; e < 32; e++){
    long off = cbase + ((long)e << 12) + l;
    float val = (acc[e] * f - zv * vmp[e] + bf2f(Tb16[off])) * bf2f(O16[off]);
    u16 h = f2bf(val);
    if (e & 1) w[e >> 1] |= ((u32)h << 16);
    else       w[e >> 1] = h;
  }
  // stage 64 B/thread into LDS, then coalesced readout (16 rows x 64 B per wave-store)
  #pragma unroll
  for (int j = 0; j < 8; j++)
    tts[tid * 9 + j] = (u64)w[2*j] | ((u64)w[2*j+1] << 32);
  __syncthreads();
  #pragma unroll
  for (int it = 0; it < 4; it++){
    int row = (tid >> 2) + 64 * it;
    int cc = tid & 3;
    u64 a  = tts[row * 9 + cc * 2];
    u64 bb = tts[row * 9 + cc * 2 + 1];
    long orow = (((long)b << 12) << 8) + ((long)(l0 + row) << 8) + n * 32 + cc * 8;
    *(uint4*)&TT16[orow] = make_uint4((u32)a, (u32)(a >> 32), (u32)bb, (u32)(bb >> 32));
  }
}

// ---------------- proj GEMM: BM=128 x BN=256, hi/lo A, 4 waves, dbuf ----------------
// [r17: ported gemmA shape, -2us] staged 64 MB, grid (16,2,8), LDS 64KB,
// waves_per_eu(2,2) protects acc+hi/lo operands from spill. hi/lo KEPT.
__global__ __launch_bounds__(256)
__attribute__((amdgpu_waves_per_eu(2, 2)))
void k_gemmP(
    const u16* __restrict__ Phi_, const u16* __restrict__ Plo_,
    const u16* __restrict__ TT16, const float* __restrict__ bias,
    float* __restrict__ out)
{
  __shared__ __align__(16) u16 AhS[2][4096];
  __shared__ __align__(16) u16 AlS[2][4096];
  __shared__ __align__(16) u16 BhS[2][8192];
  const int tid = threadIdx.x;
  const int nt = blockIdx.x, mt = blockIdx.y, b = blockIdx.z;   // nt fastest
  const int m0 = mt * 128, n0 = nt * 256;
  const int wave = tid >> 6, lane = tid & 63;
  const int wm = wave & 1, wn = wave >> 1, qu = lane >> 4, ln = lane & 15;

  const u16* bhp = TT16 + (((long)b << 12) << 8);
  const int l4 = lane >> 2, c4 = lane & 3;
  const int gch = (c4 ^ ((l4 >> 1) & 3)) * 8;
  const int fch = (qu ^ ((ln >> 1) & 3)) * 8;

  auto stage = [&](int buf, int kk){              // 8 vmem ops/thread
    #pragma unroll
    for (int t = 0; t < 2; t++){                  // A: 128 rows (hi+lo)
      int rw = wave * 32 + t * 16;
      int ga = (m0 + rw + l4) * 256 + kk + gch;
      gload16(&Phi_[ga], &AhS[buf][rw * 32]);
      gload16(&Plo_[ga], &AlS[buf][rw * 32]);
    }
    #pragma unroll
    for (int t = 0; t < 4; t++){                  // B: 256 rows
      int rwb = wave * 16 + t * 64;
      long gb = (long)(n0 + rwb + l4) * 256 + kk + gch;
      gload16(&bhp[gb], &BhS[buf][rwb * 32]);
    }
  };

  f32x4 acc[4][8];
  #pragma unroll
  for (int im = 0; im < 4; im++)
    #pragma unroll
    for (int in = 0; in < 8; in++)
      #pragma unroll
      for (int r = 0; r < 4; r++) acc[im][in][r] = 0.f;

  stage(0, 0);
  __syncthreads();

  int cur = 0;
  #pragma unroll
  for (int ks = 0; ks < 8; ks++){
    if (ks < 7) stage(cur ^ 1, (ks + 1) * 32);
    const u16* Ah = AhS[cur];
    const u16* Al = AlS[cur];
    const u16* Bc = BhS[cur];
    short8 fbh[8];
    #pragma unroll
    for (int in = 0; in < 8; in++){
      int row = wn * 128 + in * 16 + ln;         // row < 256
      fbh[in] = *(const short8*)&Bc[row * 32 + fch];
    }
    #pragma unroll
    for (int im = 0; im < 4; im++){
      int row = wm * 64 + im * 16 + ln;          // row < 128
      short8 fah = *(const short8*)&Ah[row * 32 + fch];
      short8 fal = *(const short8*)&Al[row * 32 + fch];
      #pragma unroll
      for (int in = 0; in < 8; in++){
        acc[im][in] = __builtin_amdgcn_mfma_f32_16x16x32_bf16(fah, fbh[in], acc[im][in], 0, 0, 0);
        acc[im][in] = __builtin_amdgcn_mfma_f32_16x16x32_bf16(fal, fbh[in], acc[im][in], 0, 0, 0);
      }
    }
    if (ks < 7) __syncthreads();
    cur ^= 1;
  }

  #pragma unroll
  for (int im = 0; im < 4; im++){
    int mbase = m0 + wm * 64 + im * 16 + qu * 4;
    #pragma unroll
    for (int r = 0; r < 4; r++){
      int m = mbase + r;
      float bia = bias[m];
      float* row = out + (((long)b * 256 + m) << 12);
      #pragma unroll
      for (int in = 0; in < 8; in++){
        int n = n0 + wn * 128 + in * 16 + ln;
        row[n] = acc[im][in][r] + bia;
      }
    }
  }
}

extern "C" void kernel_launch(void* const* d_in, const int* in_sizes, int n_in,
                              void* d_out, int out_size, void* d_ws, size_t ws_size,
                              hipStream_t stream)
{
  const float* x  = (const float*)d_in[0];
  const float* qw = (const float*)d_in[1];
  const float* qb = (const float*)d_in[2];
  const float* lw = (const float*)d_in[3];
  const float* lb = (const float*)d_in[4];
  const float* pw = (const float*)d_in[5];
  const float* pb = (const float*)d_in[6];

  u16* W    = (u16*)d_ws;
  u16* Q16  = W;
  u16* K16  = Q16 + 8388608;
  u16* V16  = K16 + 8388608;
  u16* O16  = V16 + 8388608;
  u16* Tb16 = O16 + 8388608;
  u16* XT   = Tb16 + 8388608;             // reused as TT16 after k_gemmA
  u16* Whi  = XT + 8388608;
  u16* Wlo  = Whi + 262144;
  u16* Phi  = Wlo + 262144;
  u16* Plo  = Phi + 65536;
  float* KMb = (float*)(Plo + 65536);
  float* VMb = KMb + 2048;
  float* KVb = VMb + 2048;
  float* SCS = KVb + 65536;
  size_t total_bytes = (6ull*8388608 + 2*262144 + 2*65536) * 2 + (2048+2048+65536+1024) * 4;
  if (ws_size < total_bytes) return;

  u16* TT16 = XT;

  k_pre<<<dim3(64, 4, 12), 256, 0, stream>>>(x, qw, pw, XT, Whi, Wlo, Phi, Plo, KMb, SCS, KVb);
  k_gemmA<<<dim3(16, 8, 8), 256, 0, stream>>>(Whi, Wlo, XT, qb, SCS,
                                              Q16, K16, V16, O16, KMb, VMb);
  k_mid<<<dim3(4, 264, 8), 256, 0, stream>>>(K16, V16, lw, lb, Tb16, KVb);
  k_res<<<dim3(16, 8, 8), 256, 0, stream>>>(Q16, KMb, KVb, VMb, O16, Tb16, SCS, TT16);
  k_gemmP<<<dim3(16, 2, 8), 256, 0, stream>>>(Phi, Plo, TT16, pb, (float*)d_out);
}

// Round 19
// 194.475 us; speedup vs baseline: 1.0095x; 1.0095x over previous
//
#include <hip/hip_runtime.h>
#include <math.h>

typedef unsigned short u16;
typedef unsigned int u32;
typedef unsigned long long u64;
typedef __attribute__((ext_vector_type(8))) short short8;
typedef __attribute__((ext_vector_type(4))) float f32x4;
typedef __attribute__((ext_vector_type(16))) float f32x16;

// B=8, C=256, H=W=64, L=4096, NH=8, HD=32. Inputs/outputs fp32.
static constexpr float SCALE = 0.17677669529663687f;          // 1/sqrt(32)
static constexpr float C2    = 0.17677669529663687f / 4096.f; // (scale/L) = c^2

__device__ __forceinline__ float bf2f(u16 u){
  union { u32 i; float f; } v; v.i = ((u32)u) << 16; return v.f;
}
__device__ __forceinline__ u16 f2bf(float f){
  union { float fl; u32 i; } v; v.fl = f;
  u32 r = v.i + 0x7fffu + ((v.i >> 16) & 1u);   // RNE
  return (u16)(r >> 16);
}
__device__ __forceinline__ float eluP(float x){ return x > 0.f ? x + 1.f : __expf(x); }
__device__ __forceinline__ float rfreq(int j){
  const float t[8] = {1.f, 0.2682695795f, 0.0719685673f, 0.0193069773f,
                      0.0051794747f, 0.0013894955f, 0.0003727594f, 1e-4f};
  return t[j];
}
// async global->LDS, 16B per lane; lds base must be wave-uniform
__device__ __forceinline__ void gload16(const u16* g, u16* l){
  __builtin_amdgcn_global_load_lds(
      (const __attribute__((address_space(1))) u32*)g,
      (__attribute__((address_space(3))) u32*)l, 16, 0, 0);
}

// ---------------- pre: x transpose + weight split + sincos table + zero buffers ----------------
// grid (64, 4, 12): z<8 -> xt for batch z; z>=8 -> weight prep (1024 virtual blocks)
__global__ __launch_bounds__(256) void k_pre(
    const float* __restrict__ x, const float* __restrict__ qw, const float* __restrict__ pw,
    u16* __restrict__ XT, u16* __restrict__ Whi, u16* __restrict__ Wlo,
    u16* __restrict__ Phi, u16* __restrict__ Plo, float* __restrict__ KM0,
    float* __restrict__ SCS, float* __restrict__ KVb)
{
  if (blockIdx.z < 8){
    __shared__ float t[64][65];
    int l0 = blockIdx.x * 64, c0 = blockIdx.y * 64, b = blockIdx.z;
    const float* xp = x + (((long)b * 256 + c0) << 12) + l0;
    #pragma unroll
    for (int rep = 0; rep < 4; rep++){
      int idx = threadIdx.x + rep * 256;
      int r = idx >> 4, ch = (idx & 15) * 4;
      float4 f = *(const float4*)&xp[((long)r << 12) + ch];
      t[r][ch] = f.x; t[r][ch+1] = f.y; t[r][ch+2] = f.z; t[r][ch+3] = f.w;
    }
    __syncthreads();
    int r2 = threadIdx.x >> 2, c8 = (threadIdx.x & 3) * 16;
    u32 w[8];
    #pragma unroll
    for (int j = 0; j < 8; j++){
      float v0 = t[c8 + 2*j][r2], v1 = t[c8 + 2*j + 1][r2];
      w[j] = (u32)f2bf(v0) | ((u32)f2bf(v1) << 16);
    }
    long ob = (((long)b << 12) << 8) + ((long)(l0 + r2) << 8) + c0 + c8;
    *(uint4*)&XT[ob]     = make_uint4(w[0], w[1], w[2], w[3]);
    *(uint4*)&XT[ob + 8] = make_uint4(w[4], w[5], w[6], w[7]);
  } else {
    int bid = (blockIdx.z - 8) * 256 + blockIdx.y * 64 + blockIdx.x;   // 0..1023
    int idx = bid * 256 + threadIdx.x;
    if (idx < 262144){
      // single-bf16 qkvo weights (lo-residual dropped: absmax unchanged at 1.22e-4,
      // error budget dominated by bf16 storage of intermediates — measured r14)
      Whi[idx] = f2bf(qw[idx]);
    }
    if (idx < 65536){
      float v = pw[idx]; u16 h = f2bf(v);
      Phi[idx] = h; Plo[idx] = f2bf(v - bf2f(h));
    }
    if (bid == 0){
      #pragma unroll
      for (int i = 0; i < 16; i++) KM0[threadIdx.x + i * 256] = 0.f;
    }
    if (bid == 1){
      // rope sincos table, computed ONCE: SCS[0..511]=sin, SCS[512..1023]=cos
      #pragma unroll
      for (int r = 0; r < 2; r++){
        int t2 = threadIdx.x + r * 256;          // 0..511
        int jj = t2 >> 6, pp = t2 & 63;
        float sn, cs; sincosf(rfreq(jj) * (float)pp, &sn, &cs);
        SCS[t2] = sn; SCS[512 + t2] = cs;
      }
    }
    if (bid >= 2 && bid < 10){
      // zero KVb (65536 floats) for k_mid's atomic accumulation
      int base = (bid - 2) * 8192 + threadIdx.x;
      #pragma unroll
      for (int i = 0; i < 32; i++) KVb[base + i * 256] = 0.f;
    }
  }
}

// ---------------- qkvo GEMM: BM=128 x BN=256, single-bf16 A, 4 waves, dbuf ----------------
// [FROZEN r16/r17 best: ~45us, HBM at floor, total 195.25] waves_per_eu(2,2)
// prevents accumulator spill (r14/r15 lesson). Staged 196 MB at the measured
// ~4.4-4.9 TB/s staging ceiling (constant across r13/r16/r18 variants — the
// structural bound). Chunk swizzle: LDS chunk c of row r = global chunk c^((r>>1)&3).
__global__ __launch_bounds__(256)
__attribute__((amdgpu_waves_per_eu(2, 2)))
void k_gemmA(
    const u16* __restrict__ Whi_, const u16* __restrict__ Wlo_,
    const u16* __restrict__ Bh_,
    const float* __restrict__ bias, const float* __restrict__ SCS_,
    u16* __restrict__ Q16, u16* __restrict__ K16,
    u16* __restrict__ V16, u16* __restrict__ O16,
    float* __restrict__ KMb, float* __restrict__ VMb)
{
  __shared__ __align__(16) u16 AhS[2][4096];
  __shared__ __align__(16) u16 BhS[2][8192];
  __shared__ float scs[2][8][64];
  const int tid = threadIdx.x;
  const int nt = blockIdx.x, mt = blockIdx.y, b = blockIdx.z;   // nt fastest
  const int m0 = mt * 128, n0 = nt * 256;
  const int wave = tid >> 6, lane = tid & 63;
  const int wm = wave & 1, wn = wave >> 1, qu = lane >> 4, ln = lane & 15;
  const int range = m0 >> 8;                 // 0:q 1:k 2:v 3:o (block-uniform)

  const u16* bhp = Bh_ + (((long)b << 12) << 8);

  const int l4 = lane >> 2, c4 = lane & 3;
  const int gch = (c4 ^ ((l4 >> 1) & 3)) * 8;     // swizzled global col chunk (store side)
  const int fch = (qu ^ ((ln >> 1) & 3)) * 8;     // fragment read swizzle (read side)

  auto stage = [&](int buf, int kk){              // 6 vmem ops/thread
    #pragma unroll
    for (int t = 0; t < 2; t++){                  // A: 128 rows
      int rw = wave * 32 + t * 16;
      int ga = (m0 + rw + l4) * 256 + kk + gch;
      gload16(&Whi_[ga], &AhS[buf][rw * 32]);
    }
    #pragma unroll
    for (int t = 0; t < 4; t++){                  // B: 256 rows
      int rwb = wave * 16 + t * 64;
      long gb = (long)(n0 + rwb + l4) * 256 + kk + gch;
      gload16(&bhp[gb], &BhS[buf][rwb * 32]);
    }
  };

  f32x4 acc[4][8];
  #pragma unroll
  for (int im = 0; im < 4; im++)
    #pragma unroll
    for (int in = 0; in < 8; in++)
      #pragma unroll
      for (int r = 0; r < 4; r++) acc[im][in][r] = 0.f;

  stage(0, 0);                               // prologue prefetch
  if (range == 1){                           // rope table: flat copy from global (no sincosf)
    #pragma unroll
    for (int r = 0; r < 4; r++){
      int idx = tid + r * 256;               // 0..1023
      ((float*)scs)[idx] = SCS_[idx];
    }
  }
  __syncthreads();                           // drains vmcnt(0): buf0 ready

  int cur = 0;
  #pragma unroll
  for (int ks = 0; ks < 8; ks++){
    if (ks < 7) stage(cur ^ 1, (ks + 1) * 32);   // issue next tile BEFORE compute
    const u16* Ah = AhS[cur];
    const u16* Bc = BhS[cur];
    short8 fbh[8];
    #pragma unroll
    for (int in = 0; in < 8; in++){
      int row = wn * 128 + in * 16 + ln;         // row < 256
      fbh[in] = *(const short8*)&Bc[row * 32 + fch];
    }
    #pragma unroll
    for (int im = 0; im < 4; im++){
      int row = wm * 64 + im * 16 + ln;          // row < 128
      short8 fah = *(const short8*)&Ah[row * 32 + fch];
      #pragma unroll
      for (int in = 0; in < 8; in++){
        acc[im][in] = __builtin_amdgcn_mfma_f32_16x16x32_bf16(fah, fbh[in], acc[im][in], 0, 0, 0);
      }
    }
    if (ks < 7) __syncthreads();             // one barrier/step
    cur ^= 1;
  }

  // epilogue: C/D layout col = lane&15 (n), row = quad*4 + reg (m)
  u16* dst = (range == 0) ? Q16 : (range == 1) ? K16 : (range == 2) ? V16 : O16;
  #pragma unroll
  for (int im = 0; im < 4; im++){
    const int mb = m0 + wm * 64 + im * 16 + qu * 4;
    float v[4][8];
    #pragma unroll
    for (int r = 0; r < 4; r++){
      float bia = bias[mb + r];
      #pragma unroll
      for (int in = 0; in < 8; in++){
        float t = acc[im][in][r] + bia;
        v[r][in] = (range < 2) ? eluP(t) : t;
      }
    }
    if (range == 1 || range == 2){
      float* mbuf = (range == 1) ? KMb : VMb;
      #pragma unroll
      for (int r = 0; r < 4; r++){
        float s = 0.f;
        #pragma unroll
        for (int in = 0; in < 8; in++) s += v[r][in];
        s += __shfl_xor(s, 1); s += __shfl_xor(s, 2);
        s += __shfl_xor(s, 4); s += __shfl_xor(s, 8);
        if (ln == 0) atomicAdd(&mbuf[b * 256 + ((mb + r) & 255)], s);
      }
    }
    if (range == 1){
      const int p0 = (mb & 31) >> 1;
      #pragma unroll
      for (int half = 0; half < 2; half++){
        int p = p0 + half, j = p & 7;
        #pragma unroll
        for (int in = 0; in < 8; in++){
          int n = n0 + wn * 128 + in * 16 + ln;
          int pos = (p < 8) ? (n >> 6) : (n & 63);
          float sn = scs[0][j][pos], cs = scs[1][j][pos];
          float a = v[2*half][in], bb = v[2*half+1][in];
          v[2*half][in]   = a * cs - bb * sn;
          v[2*half+1][in] = bb * cs + a * sn;
        }
      }
    }
    #pragma unroll
    for (int r = 0; r < 4; r++){
      u16* rowp = dst + (((long)b * 256 + ((mb + r) & 255)) << 12);
      #pragma unroll
      for (int in = 0; in < 8; in++){
        int n = n0 + wn * 128 + in * 16 + ln;
        rowp[n] = f2bf(v[r][in]);
      }
    }
  }
}

// ---------------- mid: kv (4-way L-split, 256 blocks) + lepe (8-row window reuse) ----------------
// grid (4, 264, 8): y<8 -> kv partial block; y>=8 -> lepe(ht=x, ch=y-8, b=z)
__global__ __launch_bounds__(256) void k_mid(
    const u16* __restrict__ K16, const u16* __restrict__ V16,
    const float* __restrict__ lw, const float* __restrict__ lb,
    u16* __restrict__ Tb16, float* __restrict__ KVb)
{
  if (blockIdx.y >= 8){
    __shared__ float tile[20][68];
    int ht = blockIdx.x, ch = blockIdx.y - 8, b = blockIdx.z;
    int h0 = ht * 16;
    const u16* vp = V16 + (((long)b * 256 + ch) << 12);
    const float* __restrict__ wlp = lw + ch * 25;   // block-uniform -> scalar loads
    for (int idx = threadIdx.x; idx < 20 * 68; idx += 256){
      int r = idx / 68, c = idx % 68;
      int gh = h0 + r - 2, gw = c - 2;
      float v = 0.f;
      if (gh >= 0 && gh < 64 && gw >= 0 && gw < 64) v = bf2f(vp[(gh << 6) + gw]);
      tile[r][c] = v;
    }
    __syncthreads();
    const float bia = lb[ch];
    // thread -> 4 CONSECUTIVE rows: per col j, load the 8-row strip once (40 ds_reads vs 100)
    const int ow = threadIdx.x & 63, oh0 = (threadIdx.x >> 6) * 4;
    float s0 = bia, s1 = bia, s2 = bia, s3 = bia;
    #pragma unroll
    for (int j = 0; j < 5; j++){
      float c0 = tile[oh0+0][ow+j], c1 = tile[oh0+1][ow+j];
      float c2 = tile[oh0+2][ow+j], c3 = tile[oh0+3][ow+j];
      float c4 = tile[oh0+4][ow+j], c5 = tile[oh0+5][ow+j];
      float c6 = tile[oh0+6][ow+j], c7 = tile[oh0+7][ow+j];
      float w0 = wlp[j], w1 = wlp[5+j], w2 = wlp[10+j], w3 = wlp[15+j], w4 = wlp[20+j];
      s0 += c0*w0 + c1*w1 + c2*w2 + c3*w3 + c4*w4;
      s1 += c1*w0 + c2*w1 + c3*w2 + c4*w3 + c5*w4;
      s2 += c2*w0 + c3*w1 + c4*w2 + c5*w3 + c6*w4;
      s3 += c3*w0 + c4*w1 + c5*w2 + c6*w3 + c7*w4;
    }
    u16* tp = Tb16 + (((long)b * 256 + ch) << 12) + ((h0 + oh0) << 6) + ow;
    tp[0]   = f2bf(s0);
    tp[64]  = f2bf(s1);
    tp[128] = f2bf(s2);
    tp[192] = f2bf(s3);
  } else {
    __shared__ float red[4][1024];
    int kvIdx = blockIdx.y * 32 + blockIdx.z * 4 + blockIdx.x;   // 0..255
    int seg = kvIdx >> 6, rem = kvIdx & 63;
    int n = rem & 7, b = rem >> 3;
    const int tid = threadIdx.x, wave = tid >> 6, lane = tid & 63;
    const u16* kp = K16 + (((long)(b * 256 + n * 32)) << 12);
    const u16* vp = V16 + (((long)(b * 256 + n * 32)) << 12);
    const int m = lane & 31, kh = lane >> 5;
    const long row = ((long)m << 12);
    const int lbase = seg * 1024 + wave * 256;

    f32x16 acc;
    #pragma unroll
    for (int r = 0; r < 16; r++) acc[r] = 0.f;
    #pragma unroll 4
    for (int it = 0; it < 16; it++){
      int l = lbase + it * 16 + kh * 8;
      short8 a  = *(const short8*)&kp[row + l];
      short8 bf = *(const short8*)&vp[row + l];
      acc = __builtin_amdgcn_mfma_f32_32x32x16_bf16(a, bf, acc, 0, 0, 0);
    }
    #pragma unroll
    for (int reg = 0; reg < 16; reg++){
      int rr = (reg & 3) + 8 * (reg >> 2) + 4 * kh;
      red[wave][rr * 32 + m] = acc[reg];
    }
    __syncthreads();
    #pragma unroll
    for (int i = tid; i < 1024; i += 256){
      float s = red[0][i] + red[1][i] + red[2][i] + red[3][i];
      atomicAdd(&KVb[(((long)b * 8 + n) << 10) + i], s * C2);
    }
  }
}

// ---------------- res (+fused z): 256-thread blocks, uniform scalar kv/km/vm ----------------
__global__ __launch_bounds__(256) void k_res(
    const u16* __restrict__ Q16, const float* __restrict__ KMb,
    const float* __restrict__ KVb, const float* __restrict__ VMb,
    const u16* __restrict__ O16, const u16* __restrict__ Tb16,
    const float* __restrict__ SCS_, u16* __restrict__ TT16)
{
  __shared__ float scs[2][8][64];
  __shared__ __align__(16) u64 tts[256 * 9];   // [l][8 u64 + 1 pad]
  const int b = blockIdx.z, n = blockIdx.y, tid = threadIdx.x;
  #pragma unroll
  for (int r = 0; r < 4; r++){
    int idx = tid + r * 256;                 // 0..1023
    ((float*)scs)[idx] = SCS_[idx];
  }
  __syncthreads();

  const float* __restrict__ kv  = KVb + (((long)b * 8 + n) << 10);  // uniform
  const float* __restrict__ kmp = KMb + b * 256 + n * 32;           // uniform
  const float* __restrict__ vmp = VMb + b * 256 + n * 32;           // uniform

  const int l0 = blockIdx.x * 256;
  const int l = l0 + tid;
  const long cbase = ((long)(b * 256 + n * 32)) << 12;

  float q[32];
  #pragma unroll
  for (int d = 0; d < 32; d++) q[d] = bf2f(Q16[cbase + ((long)d << 12) + l]);
  float z = 0.f;
  #pragma unroll
  for (int d = 0; d < 32; d++) z += q[d] * kmp[d];
  z *= SCALE * (1.f / 4096.f);
  #pragma unroll
  for (int p = 0; p < 16; p++){
    int pos = (p < 8) ? (l >> 6) : (l & 63);
    float sn = scs[0][p & 7][pos], cs = scs[1][p & 7][pos];
    float q0 = q[2*p], q1 = q[2*p+1];
    q[2*p]   = q0 * cs - q1 * sn;
    q[2*p+1] = q1 * cs + q0 * sn;
  }

  float acc[32];
  #pragma unroll
  for (int e = 0; e < 32; e++) acc[e] = 0.f;
  #pragma unroll 8
  for (int d = 0; d < 32; d++){
    float qd = q[d];
    #pragma unroll
    for (int ec = 0; ec < 8; ec++){
      float4 kvv = *(const float4*)&kv[d * 32 + ec * 4];   // uniform -> scalar
      acc[ec*4+0] += qd * kvv.x;
      acc[ec*4+1] += qd * kvv.y;
      acc[ec*4+2] += qd * kvv.z;
      acc[ec*4+3] += qd * kvv.w;
    }
  }

  const float f = 1.f + 1.f / (z + 1e-6f);
  const float zv = z * (1.f / 4096.f);
  u32 w[16];
  #pragma unroll
  for (int e = 0; e < 32; e++){
    long off = cbase + ((long)e << 12) + l;
    float val = (acc[e] * f - zv * vmp[e] + bf2f(Tb16[off])) * bf2f(O16[off]);
    u16 h = f2bf(val);
    if (e & 1) w[e >> 1] |= ((u32)h << 16);
    else       w[e >> 1] = h;
  }
  // stage 64 B/thread into LDS, then coalesced readout (16 rows x 64 B per wave-store)
  #pragma unroll
  for (int j = 0; j < 8; j++)
    tts[tid * 9 + j] = (u64)w[2*j] | ((u64)w[2*j+1] << 32);
  __syncthreads();
  #pragma unroll
  for (int it = 0; it < 4; it++){
    int row = (tid >> 2) + 64 * it;
    int cc = tid & 3;
    u64 a  = tts[row * 9 + cc * 2];
    u64 bb = tts[row * 9 + cc * 2 + 1];
    long orow = (((long)b << 12) << 8) + ((long)(l0 + row) << 8) + n * 32 + cc * 8;
    *(uint4*)&TT16[orow] = make_uint4((u32)a, (u32)(a >> 32), (u32)bb, (u32)(bb >> 32));
  }
}

// ---------------- proj GEMM: BM=128 x BN=256, hi/lo A, 4 waves, dbuf ----------------
// [r17: ported gemmA shape, -2us] staged 64 MB, grid (16,2,8), LDS 64KB,
// waves_per_eu(2,2) protects acc+hi/lo operands from spill. hi/lo KEPT.
__global__ __launch_bounds__(256)
__attribute__((amdgpu_waves_per_eu(2, 2)))
void k_gemmP(
    const u16* __restrict__ Phi_, const u16* __restrict__ Plo_,
    const u16* __restrict__ TT16, const float* __restrict__ bias,
    float* __restrict__ out)
{
  __shared__ __align__(16) u16 AhS[2][4096];
  __shared__ __align__(16) u16 AlS[2][4096];
  __shared__ __align__(16) u16 BhS[2][8192];
  const int tid = threadIdx.x;
  const int nt = blockIdx.x, mt = blockIdx.y, b = blockIdx.z;   // nt fastest
  const int m0 = mt * 128, n0 = nt * 256;
  const int wave = tid >> 6, lane = tid & 63;
  const int wm = wave & 1, wn = wave >> 1, qu = lane >> 4, ln = lane & 15;

  const u16* bhp = TT16 + (((long)b << 12) << 8);
  const int l4 = lane >> 2, c4 = lane & 3;
  const int gch = (c4 ^ ((l4 >> 1) & 3)) * 8;
  const int fch = (qu ^ ((ln >> 1) & 3)) * 8;

  auto stage = [&](int buf, int kk){              // 8 vmem ops/thread
    #pragma unroll
    for (int t = 0; t < 2; t++){                  // A: 128 rows (hi+lo)
      int rw = wave * 32 + t * 16;
      int ga = (m0 + rw + l4) * 256 + kk + gch;
      gload16(&Phi_[ga], &AhS[buf][rw * 32]);
      gload16(&Plo_[ga], &AlS[buf][rw * 32]);
    }
    #pragma unroll
    for (int t = 0; t < 4; t++){                  // B: 256 rows
      int rwb = wave * 16 + t * 64;
      long gb = (long)(n0 + rwb + l4) * 256 + kk + gch;
      gload16(&bhp[gb], &BhS[buf][rwb * 32]);
    }
  };

  f32x4 acc[4][8];
  #pragma unroll
  for (int im = 0; im < 4; im++)
    #pragma unroll
    for (int in = 0; in < 8; in++)
      #pragma unroll
      for (int r = 0; r < 4; r++) acc[im][in][r] = 0.f;

  stage(0, 0);
  __syncthreads();

  int cur = 0;
  #pragma unroll
  for (int ks = 0; ks < 8; ks++){
    if (ks < 7) stage(cur ^ 1, (ks + 1) * 32);
    const u16* Ah = AhS[cur];
    const u16* Al = AlS[cur];
    const u16* Bc = BhS[cur];
    short8 fbh[8];
    #pragma unroll
    for (int in = 0; in < 8; in++){
      int row = wn * 128 + in * 16 + ln;         // row < 256
      fbh[in] = *(const short8*)&Bc[row * 32 + fch];
    }
    #pragma unroll
    for (int im = 0; im < 4; im++){
      int row = wm * 64 + im * 16 + ln;          // row < 128
      short8 fah = *(const short8*)&Ah[row * 32 + fch];
      short8 fal = *(const short8*)&Al[row * 32 + fch];
      #pragma unroll
      for (int in = 0; in < 8; in++){
        acc[im][in] = __builtin_amdgcn_mfma_f32_16x16x32_bf16(fah, fbh[in], acc[im][in], 0, 0, 0);
        acc[im][in] = __builtin_amdgcn_mfma_f32_16x16x32_bf16(fal, fbh[in], acc[im][in], 0, 0, 0);
      }
    }
    if (ks < 7) __syncthreads();
    cur ^= 1;
  }

  #pragma unroll
  for (int im = 0; im < 4; im++){
    int mbase = m0 + wm * 64 + im * 16 + qu * 4;
    #pragma unroll
    for (int r = 0; r < 4; r++){
      int m = mbase + r;
      float bia = bias[m];
      float* row = out + (((long)b * 256 + m) << 12);
      #pragma unroll
      for (int in = 0; in < 8; in++){
        int n = n0 + wn * 128 + in * 16 + ln;
        row[n] = acc[im][in][r] + bia;
      }
    }
  }
}

extern "C" void kernel_launch(void* const* d_in, const int* in_sizes, int n_in,
                              void* d_out, int out_size, void* d_ws, size_t ws_size,
                              hipStream_t stream)
{
  const float* x  = (const float*)d_in[0];
  const float* qw = (const float*)d_in[1];
  const float* qb = (const float*)d_in[2];
  const float* lw = (const float*)d_in[3];
  const float* lb = (const float*)d_in[4];
  const float* pw = (const float*)d_in[5];
  const float* pb = (const float*)d_in[6];

  u16* W    = (u16*)d_ws;
  u16* Q16  = W;
  u16* K16  = Q16 + 8388608;
  u16* V16  = K16 + 8388608;
  u16* O16  = V16 + 8388608;
  u16* Tb16 = O16 + 8388608;
  u16* XT   = Tb16 + 8388608;             // reused as TT16 after k_gemmA
  u16* Whi  = XT + 8388608;
  u16* Wlo  = Whi + 262144;
  u16* Phi  = Wlo + 262144;
  u16* Plo  = Phi + 65536;
  float* KMb = (float*)(Plo + 65536);
  float* VMb = KMb + 2048;
  float* KVb = VMb + 2048;
  float* SCS = KVb + 65536;
  size_t total_bytes = (6ull*8388608 + 2*262144 + 2*65536) * 2 + (2048+2048+65536+1024) * 4;
  if (ws_size < total_bytes) return;

  u16* TT16 = XT;

  k_pre<<<dim3(64, 4, 12), 256, 0, stream>>>(x, qw, pw, XT, Whi, Wlo, Phi, Plo, KMb, SCS, KVb);
  k_gemmA<<<dim3(16, 8, 8), 256, 0, stream>>>(Whi, Wlo, XT, qb, SCS,
                                              Q16, K16, V16, O16, KMb, VMb);
  k_mid<<<dim3(4, 264, 8), 256, 0, stream>>>(K16, V16, lw, lb, Tb16, KVb);
  k_res<<<dim3(16, 8, 8), 256, 0, stream>>>(Q16, KMb, KVb, VMb, O16, Tb16, SCS, TT16);
  k_gemmP<<<dim3(16, 2, 8), 256, 0, stream>>>(Phi, Plo, TT16, pb, (float*)d_out);
}